// Round 7
// baseline (19.491 us; speedup 1.0000x reference)
//
#include <hip/hip_runtime.h>

// ---------------- types / helpers ----------------
typedef short bf16x8 __attribute__((ext_vector_type(8)));
typedef float f32x4 __attribute__((ext_vector_type(4)));

#define NEGV -1000000000.0f
#define WINI 3584          // cube_mask window ints (14 KB LDS); +-1280 = 3.6 sigma coverage

__device__ __forceinline__ unsigned short f2bf(float f) {
    unsigned int u = __float_as_uint(f);
    u += 0x7FFFu + ((u >> 16) & 1u);   // round-to-nearest-even
    return (unsigned short)(u >> 16);
}

// ---------------- prep: batch segment boundaries (int4) + weight transpose ----------------
__global__ void prep_kernel(const float* __restrict__ W1, const float* __restrict__ W2,
                            const int* __restrict__ batch, int N, int B,
                            int* __restrict__ batch_start,
                            unsigned short* __restrict__ w1t, unsigned short* __restrict__ w2t) {
    int idx = blockIdx.x * 256 + threadIdx.x;
    int i0 = idx * 4;
    if (i0 < N) {                          // N divisible by 4
        int4 v = *(const int4*)(batch + i0);
        int prev = (i0 == 0) ? -1 : batch[i0 - 1];
        const int* vv = (const int*)&v;
#pragma unroll
        for (int j = 0; j < 4; ++j) {
            int i = i0 + j;
            if (i < N) {
                int b = vv[j];
                if (b != prev) { for (int bb = prev + 1; bb <= b; ++bb) batch_start[bb] = i; }
                if (i == N - 1) { for (int bb = b + 1; bb <= B; ++bb) batch_start[bb] = N; }
                prev = b;
            }
        }
    }
    if (idx < 128 * 256) {                 // W1T[col][k] = W1[k][col], bf16
        int col = idx >> 8, k = idx & 255;
        w1t[col * 256 + k] = f2bf(W1[k * 128 + col]);
    }
    if (idx < 32 * 128) {                  // W2T[col][k] = W2[k][col], pad col>=24 with 0
        int col = idx >> 7, k = idx & 127;
        w2t[col * 128 + k] = (col < 24) ? f2bf(W2[k * 24 + col]) : (unsigned short)0;
    }
}

// ---------------- fused: per-batch slot scan + gather + MLP + masked write ----------------
// One block per batch b (512 blocks = exactly 2/CU, 256 threads = 4 waves).
// cube_mask window prefetched at cycle 0 via the statistical estimate of segs
// (issued parallel with batch_start), staged to LDS; double-buffered ldsA/ldsB;
// chunk order gf,gf,nf,nf hides the nf gather under MFMA.
__global__ void __launch_bounds__(256, 2)
fused_kernel(const float* __restrict__ nf, const float* __restrict__ gf,
             const unsigned short* __restrict__ w1t, const unsigned short* __restrict__ w2t,
             const float* __restrict__ b1, const float* __restrict__ b2,
             const int* __restrict__ cube_mask, const int* __restrict__ batch_start,
             const int* __restrict__ move_mask, float* __restrict__ out, int N, int B) {
    // buf0: A0[64][72] | B0[128][72]; buf1 likewise; ldsH aliases buf0
    __shared__ __align__(16) char smem[(64 * 72 + 128 * 72) * 2 * 2];
    __shared__ __align__(16) unsigned short ldsW2[32][136];
    __shared__ __align__(16) int ldsWin[WINI];
    __shared__ int lds_node[64];
    __shared__ int wt[4];
    unsigned short (*ldsA0)[72]  = (unsigned short (*)[72])smem;
    unsigned short (*ldsB0)[72]  = (unsigned short (*)[72])(smem + 9216);
    unsigned short (*ldsA1)[72]  = (unsigned short (*)[72])(smem + 27648);
    unsigned short (*ldsB1)[72]  = (unsigned short (*)[72])(smem + 27648 + 9216);
    unsigned short (*ldsH)[136]  = (unsigned short (*)[136])smem;

    int t = threadIdx.x;
    int blk = blockIdx.x;
    int lane = t & 63, w = t >> 6;
    int wm = w >> 1, wn = w & 1;         // wave tile: rows [wm*32,+32), cols [wn*64,+64)
    int r = t >> 2, q = t & 3;           // A staging: row, quarter (16 floats)
    int bcol = t >> 1, bh0 = (t & 1) * 32;   // B staging coords

    // ---- chain head: segment bounds ----
    int segs = batch_start[blk], sege = batch_start[blk + 1];

    // ---- cube_mask window at the statistical estimate: issue at cycle 0 ----
    int est = (int)(((long long)blk * N) / B);
    int wstart = est - 1280;
    if (wstart < 0) wstart = 0;
    if (wstart > N - WINI) wstart = N - WINI;
    wstart &= ~3;
    int4 wv4[3];
    int2 wv2;
    {
        const int* wsrc = cube_mask + wstart;
#pragma unroll
        for (int j = 0; j < 3; ++j) wv4[j] = *(const int4*)(wsrc + j * 1024 + t * 4);
        wv2 = *(const int2*)(wsrc + 3072 + t * 2);
    }

    if (t < 64) lds_node[t] = -1;

    // ---- independent prefetches (in flight while segs/window resolve) ----
    int w2col = t >> 3, w2k0 = (t & 7) * 16;
    bf16x8 w2a, w2b;
    {
        const unsigned short* src = w2t + w2col * 128 + w2k0;
        w2a = *(const bf16x8*)(src);
        w2b = *(const bf16x8*)(src + 8);
    }
    bf16x8 fB[4];
#define LOAD_W1(ch) do {                                                         \
        const unsigned short* srcB = w1t + bcol * 256 + (ch) * 64 + bh0;         \
        fB[0] = *(const bf16x8*)(srcB);      fB[1] = *(const bf16x8*)(srcB + 8); \
        fB[2] = *(const bf16x8*)(srcB + 16); fB[3] = *(const bf16x8*)(srcB + 24);\
    } while (0)
    LOAD_W1(2);                          // gf-lo weights (k 128..191)
    float4 fGl[4], fGh[4];
    {
        const float* srcG = gf + (size_t)blk * 128 + q * 16;
#pragma unroll
        for (int i = 0; i < 4; ++i) {
            fGl[i] = *(const float4*)(srcG + i * 4);
            fGh[i] = *(const float4*)(srcG + 64 + i * 4);
        }
    }
    float b1v[4];
#pragma unroll
    for (int nt = 0; nt < 4; ++nt) b1v[nt] = b1[wn * 64 + nt * 16 + (lane & 15)];
    float b2v[2];
    int mmv[8];
#pragma unroll
    for (int ct = 0; ct < 2; ++ct) {
        int m = ct * 16 + (lane & 15);
        if (m < 24) {
            b2v[ct] = b2[m];
#pragma unroll
            for (int rr = 0; rr < 4; ++rr) {
                int row = w * 16 + (lane >> 4) * 4 + rr;
                mmv[ct * 4 + rr] = move_mask[(size_t)(blk * 64 + row) * 24 + m];
            }
        } else {
            b2v[ct] = 0.f;
#pragma unroll
            for (int rr = 0; rr < 4; ++rr) mmv[ct * 4 + rr] = 0;
        }
    }

    // ---- stage window, buf0 (gf-lo x W1ch2), ldsW2 ----
#pragma unroll
    for (int j = 0; j < 3; ++j) *(int4*)&ldsWin[j * 1024 + t * 4] = wv4[j];
    *(int2*)&ldsWin[3072 + t * 2] = wv2;

#define STAGE_A(AB, s0, s1, s2, s3) do {                                         \
        unsigned short tmp[16];                                                  \
        tmp[0]  = f2bf((s0).x); tmp[1]  = f2bf((s0).y); tmp[2]  = f2bf((s0).z); tmp[3]  = f2bf((s0).w); \
        tmp[4]  = f2bf((s1).x); tmp[5]  = f2bf((s1).y); tmp[6]  = f2bf((s1).z); tmp[7]  = f2bf((s1).w); \
        tmp[8]  = f2bf((s2).x); tmp[9]  = f2bf((s2).y); tmp[10] = f2bf((s2).z); tmp[11] = f2bf((s2).w); \
        tmp[12] = f2bf((s3).x); tmp[13] = f2bf((s3).y); tmp[14] = f2bf((s3).z); tmp[15] = f2bf((s3).w); \
        *(bf16x8*)&AB[r][q * 16]     = *(bf16x8*)&tmp[0];                        \
        *(bf16x8*)&AB[r][q * 16 + 8] = *(bf16x8*)&tmp[8];                        \
    } while (0)
#define STAGE_B(BB) do {                                                         \
        *(bf16x8*)&BB[bcol][bh0]      = fB[0];                                   \
        *(bf16x8*)&BB[bcol][bh0 + 8]  = fB[1];                                   \
        *(bf16x8*)&BB[bcol][bh0 + 16] = fB[2];                                   \
        *(bf16x8*)&BB[bcol][bh0 + 24] = fB[3];                                   \
    } while (0)
#define MFMA_CHUNK(AA, BB) do {                                                  \
        _Pragma("unroll")                                                        \
        for (int ks = 0; ks < 2; ++ks) {                                         \
            int ko = ks * 32 + (lane >> 4) * 8;                                  \
            bf16x8 af[2], bfr[4];                                                \
            _Pragma("unroll")                                                    \
            for (int mt = 0; mt < 2; ++mt)                                       \
                af[mt] = *(const bf16x8*)&AA[wm * 32 + mt * 16 + (lane & 15)][ko]; \
            _Pragma("unroll")                                                    \
            for (int nt = 0; nt < 4; ++nt)                                       \
                bfr[nt] = *(const bf16x8*)&BB[wn * 64 + nt * 16 + (lane & 15)][ko]; \
            _Pragma("unroll")                                                    \
            for (int mt = 0; mt < 2; ++mt)                                       \
                _Pragma("unroll")                                                \
                for (int nt = 0; nt < 4; ++nt)                                   \
                    acc[mt][nt] = __builtin_amdgcn_mfma_f32_16x16x32_bf16(       \
                        af[mt], bfr[nt], acc[mt][nt], 0, 0, 0);                  \
        }                                                                        \
    } while (0)

    *(bf16x8*)&ldsW2[w2col][w2k0]     = w2a;
    *(bf16x8*)&ldsW2[w2col][w2k0 + 8] = w2b;
    STAGE_A(ldsA0, fGl[0], fGl[1], fGl[2], fGl[3]);
    STAGE_B(ldsB0);
    LOAD_W1(3);                          // gf-hi weights

    f32x4 acc[2][4];
#pragma unroll
    for (int i = 0; i < 2; ++i)
#pragma unroll
        for (int j = 0; j < 4; ++j) acc[i][j] = (f32x4){0.f, 0.f, 0.f, 0.f};

    __syncthreads();                     // sync1: window + buf0 + ldsW2 + lds_node init

    // ---- cube window read (LDS fast path; uniform global fallback) ----
    int base = segs & ~3;
    if (base > N - 1024) base = (N - 1024) & ~3;
    int off = base - wstart;
    int4 cmv;
    if (off >= 0 && off <= WINI - 1024) {
        cmv = *(const int4*)&ldsWin[off + t * 4];
    } else {
        cmv = *(const int4*)(cube_mask + base + t * 4);   // rare: >3.6 sigma deviation
    }

    // stage buf1 (gf-hi x W1ch3); prefetch nf-lo weights
    STAGE_A(ldsA1, fGh[0], fGh[1], fGh[2], fGh[3]);
    STAGE_B(ldsB1);
    LOAD_W1(0);

    // one-shot cube count + wave prefix
    int c_t = 0;
#pragma unroll
    for (int j = 0; j < 4; ++j) {
        int i = base + t * 4 + j;
        int mk = ((const int*)&cmv)[j];
        c_t += (i >= segs && i < sege && mk != 0) ? 1 : 0;
    }
    int inc = c_t;
#pragma unroll
    for (int d = 1; d < 64; d <<= 1) {
        int o = __shfl_up(inc, d);
        if (lane >= d) inc += o;
    }
    if (lane == 63) wt[w] = inc;

    MFMA_CHUNK(ldsA0, ldsB0);            // ch2: gf-lo
    __syncthreads();                     // sync2: buf1 + wt ready

    int waveOfs = 0, total = 0;
#pragma unroll
    for (int j = 0; j < 4; ++j) { int c = wt[j]; if (j < w) waveOfs += c; total += c; }
    {
        int rank = waveOfs + (inc - c_t);
#pragma unroll
        for (int j = 0; j < 4; ++j) {
            int i = base + t * 4 + j;
            int mk = ((const int*)&cmv)[j];
            if (i >= segs && i < sege && mk != 0) {
                if (rank < 64) lds_node[rank] = i;
                ++rank;
            }
        }
    }
    // overflow fallback (rare: <64 cubes in first ~1021 nodes of a bigger segment)
    int found = total;
    for (int pos = base + 1024; pos < sege && found < 64; pos += 256) {
        int i = pos + t;
        int mk = (i < sege) ? cube_mask[i] : 0;
        unsigned long long bal = __ballot(mk != 0);
        int below = __popcll(bal & ((1ULL << lane) - 1ULL));
        __syncthreads();                 // protect prior wt readers
        if (lane == 0) wt[w] = __popcll(bal);
        __syncthreads();
        int wofs = 0, tot = 0;
#pragma unroll
        for (int j = 0; j < 4; ++j) { int c = wt[j]; if (j < w) wofs += c; tot += c; }
        int rk = found + wofs + below;
        if (mk && rk < 64) lds_node[rk] = i;
        found += tot;
    }
    __syncthreads();                     // sync3: lds_node final

    // issue nf gather immediately; ch3 MFMA + staging hide its latency
    int n = lds_node[r];
    int nrow = (n >= 0) ? n : 0;
    const float* srcN = nf + (size_t)nrow * 128 + q * 16;
    float4 fN[8];
#pragma unroll
    for (int i = 0; i < 4; ++i) {
        fN[i]     = *(const float4*)(srcN + i * 4);
        fN[4 + i] = *(const float4*)(srcN + 64 + i * 4);
    }

    MFMA_CHUNK(ldsA1, ldsB1);            // ch3: gf-hi
    STAGE_B(ldsB0);                      // W1 ch0 -> B0
    LOAD_W1(1);                          // nf-hi weights
    STAGE_A(ldsA0, fN[0], fN[1], fN[2], fN[3]);   // waits on fN
    __syncthreads();                     // sync4: buf0 = nf-lo

    MFMA_CHUNK(ldsA0, ldsB0);            // ch0: nf-lo
    STAGE_A(ldsA1, fN[4], fN[5], fN[6], fN[7]);
    STAGE_B(ldsB1);                      // W1 ch1 -> B1
    __syncthreads();                     // sync5: buf1 = nf-hi

    MFMA_CHUNK(ldsA1, ldsB1);            // ch1: nf-hi

#undef STAGE_A
#undef STAGE_B
#undef LOAD_W1
#undef MFMA_CHUNK

    // layer1 epilogue: bias + relu -> ldsH (aliases buf0; last buf0 reader was ch0, pre-sync5)
#pragma unroll
    for (int nt = 0; nt < 4; ++nt) {
        int col = wn * 64 + nt * 16 + (lane & 15);
        float bias = b1v[nt];
#pragma unroll
        for (int mt = 0; mt < 2; ++mt) {
            int row0 = wm * 32 + mt * 16 + (lane >> 4) * 4;
#pragma unroll
            for (int rr = 0; rr < 4; ++rr) {
                float v = acc[mt][nt][rr] + bias;
                v = v > 0.f ? v : 0.f;
                ldsH[row0 + rr][col] = f2bf(v);
            }
        }
    }
    __syncthreads();                     // sync6: ldsH ready

    // layer2: wave w rows [w*16,+16); K=128 in 4 steps; cols 0..31 (pad of 24)
    f32x4 acc2[2];
    acc2[0] = (f32x4){0.f, 0.f, 0.f, 0.f};
    acc2[1] = (f32x4){0.f, 0.f, 0.f, 0.f};
#pragma unroll
    for (int ks = 0; ks < 4; ++ks) {
        int ko = ks * 32 + (lane >> 4) * 8;
        bf16x8 a2 = *(const bf16x8*)&ldsH[w * 16 + (lane & 15)][ko];
#pragma unroll
        for (int ct = 0; ct < 2; ++ct) {
            bf16x8 bw = *(const bf16x8*)&ldsW2[ct * 16 + (lane & 15)][ko];
            acc2[ct] = __builtin_amdgcn_mfma_f32_16x16x32_bf16(a2, bw, acc2[ct], 0, 0, 0);
        }
    }

    // write out: every (slot, m<24) element written exactly once per call
#pragma unroll
    for (int ct = 0; ct < 2; ++ct) {
        int m = ct * 16 + (lane & 15);
        if (m >= 24) continue;
#pragma unroll
        for (int rr = 0; rr < 4; ++rr) {
            int row = w * 16 + (lane >> 4) * 4 + rr;
            size_t oidx = (size_t)(blk * 64 + row) * 24 + m;
            float v = acc2[ct][rr] + b2v[ct];
            bool keep = (lds_node[row] >= 0) && (mmv[ct * 4 + rr] != 0);
            out[oidx] = keep ? v : NEGV;
        }
    }
}

// ---------------- launcher ----------------
extern "C" void kernel_launch(void* const* d_in, const int* in_sizes, int n_in,
                              void* d_out, int out_size, void* d_ws, size_t ws_size,
                              hipStream_t stream) {
    const float* nf = (const float*)d_in[0];
    const float* gf = (const float*)d_in[1];
    const float* W1 = (const float*)d_in[2];
    const float* b1 = (const float*)d_in[3];
    const float* W2 = (const float*)d_in[4];
    const float* b2 = (const float*)d_in[5];
    const int* cube_mask = (const int*)d_in[6];
    const int* batch     = (const int*)d_in[7];
    const int* move_mask = (const int*)d_in[8];
    float* out = (float*)d_out;

    int N = in_sizes[6];            // 500000
    int B = in_sizes[1] / 128;      // 512

    char* ws = (char*)d_ws;
    int* batch_start = (int*)(ws);                         // B+1 ints
    unsigned short* w1t = (unsigned short*)(ws + 4096);    // 128*256 bf16 (64 KB)
    unsigned short* w2t = (unsigned short*)(ws + 69632);   // 32*128 bf16 (8 KB)

    int NB = (N + 1023) / 1024;     // 489 (int4: 4 nodes/thread)
    prep_kernel<<<NB, 256, 0, stream>>>(W1, W2, batch, N, B, batch_start, w1t, w2t);
    fused_kernel<<<B, 256, 0, stream>>>(nf, gf, w1t, w2t, b1, b2,
                                        cube_mask, batch_start, move_mask, out, N, B);
    (void)n_in; (void)out_size; (void)ws_size;
}

// Round 8
// 17.507 us; speedup vs baseline: 1.1133x; 1.1133x over previous
//
#include <hip/hip_runtime.h>

// ---------------- types / helpers ----------------
typedef short bf16x8 __attribute__((ext_vector_type(8)));
typedef float f32x4 __attribute__((ext_vector_type(4)));

#define NEGV -1000000000.0f

__device__ __forceinline__ unsigned short f2bf(float f) {
    unsigned int u = __float_as_uint(f);
    u += 0x7FFFu + ((u >> 16) & 1u);   // round-to-nearest-even
    return (unsigned short)(u >> 16);
}

// ---------------- prep: batch segment boundaries + weight transpose ----------------
__global__ void prep_kernel(const float* __restrict__ W1, const float* __restrict__ W2,
                            const int* __restrict__ batch, int N, int B,
                            int* __restrict__ batch_start,
                            unsigned short* __restrict__ w1t, unsigned short* __restrict__ w2t) {
    int idx = blockIdx.x * 256 + threadIdx.x;
    if (idx < N) {
        int bcur = batch[idx];
        if (idx == 0) {
            for (int bb = 0; bb <= bcur; ++bb) batch_start[bb] = 0;
        } else {
            int bprev = batch[idx - 1];
            for (int bb = bprev + 1; bb <= bcur; ++bb) batch_start[bb] = idx;
        }
        if (idx == N - 1) {
            for (int bb = bcur + 1; bb <= B; ++bb) batch_start[bb] = N;
        }
    }
    if (idx < 128 * 256) {                 // W1T[col][k] = W1[k][col], bf16
        int col = idx >> 8, k = idx & 255;
        w1t[col * 256 + k] = f2bf(W1[k * 128 + col]);
    }
    if (idx < 32 * 128) {                  // W2T[col][k] = W2[k][col], pad col>=24 with 0
        int col = idx >> 7, k = idx & 127;
        w2t[col * 128 + k] = (col < 24) ? f2bf(W2[k * 24 + col]) : (unsigned short)0;
    }
}

// ---------------- fused: per-batch slot scan + gather + MLP + masked write ----------------
// One block per batch b (512 blocks, 256 threads = 4 waves, 3 blocks/CU).
// ldsH aliases ldsA/ldsB (dead after the K-loop) to cut LDS 54->37 KB.
__global__ void __launch_bounds__(256, 3)
fused_kernel(const float* __restrict__ nf, const float* __restrict__ gf,
             const unsigned short* __restrict__ w1t, const unsigned short* __restrict__ w2t,
             const float* __restrict__ b1, const float* __restrict__ b2,
             const int* __restrict__ cube_mask, const int* __restrict__ batch_start,
             const int* __restrict__ move_mask, float* __restrict__ out) {
    __shared__ __align__(16) char smemAB[(64 * 72 + 128 * 72) * 2];   // ldsA | ldsB, aliased by ldsH
    __shared__ __align__(16) unsigned short ldsW2[32][136];
    __shared__ int lds_node[64];
    __shared__ int wt[4];
    unsigned short (*ldsA)[72]  = (unsigned short (*)[72])smemAB;
    unsigned short (*ldsB)[72]  = (unsigned short (*)[72])(smemAB + 64 * 72 * 2);
    unsigned short (*ldsH)[136] = (unsigned short (*)[136])smemAB;

    int t = threadIdx.x;
    int blk = blockIdx.x;            // batch index
    int lane = t & 63, w = t >> 6;   // wave id 0..3

    // ---- dependent chain head: issue ASAP ----
    int segs = batch_start[blk], sege = batch_start[blk + 1];

    if (t < 64) lds_node[t] = -1;

    // ---- independent prefetches (overlap the phase-1 latency chain) ----
    {   // stage W2T once: 32x128 bf16, 16 elems per thread
        int col = t >> 3;
        int k0 = (t & 7) * 16;
        const unsigned short* src = w2t + col * 128 + k0;
        *(bf16x8*)&ldsW2[col][k0]     = *(const bf16x8*)(src);
        *(bf16x8*)&ldsW2[col][k0 + 8] = *(const bf16x8*)(src + 8);
    }
    int bcol = t >> 1, bh0 = (t & 1) * 32;
    bf16x8 fB[4];
    {   // W1T chunk 0 into regs
        const unsigned short* srcB = w1t + bcol * 256 + bh0;
        fB[0] = *(const bf16x8*)(srcB);      fB[1] = *(const bf16x8*)(srcB + 8);
        fB[2] = *(const bf16x8*)(srcB + 16); fB[3] = *(const bf16x8*)(srcB + 24);
    }
    int wm = w >> 1, wn = w & 1;     // wave tile: rows [wm*32,+32), cols [wn*64,+64)
    float b1v[4];
#pragma unroll
    for (int nt = 0; nt < 4; ++nt) b1v[nt] = b1[wn * 64 + nt * 16 + (lane & 15)];
    float b2v[2];
    int mmv[8];
#pragma unroll
    for (int ct = 0; ct < 2; ++ct) {
        int m = ct * 16 + (lane & 15);
        if (m < 24) {
            b2v[ct] = b2[m];
#pragma unroll
            for (int rr = 0; rr < 4; ++rr) {
                int row = w * 16 + (lane >> 4) * 4 + rr;
                mmv[ct * 4 + rr] = move_mask[(size_t)(blk * 64 + row) * 24 + m];
            }
        } else {
            b2v[ct] = 0.f;
#pragma unroll
            for (int rr = 0; rr < 4; ++rr) mmv[ct * 4 + rr] = 0;
        }
    }
    __syncthreads();                 // lds_node init + ldsW2 visible

    // ---- phase 1: find first 64 cubes in [segs, sege) ----
    int found = 0;
    for (int pos = segs; pos < sege && found < 64; pos += 256) {
        int i = pos + t;
        int m = (i < sege) ? cube_mask[i] : 0;
        unsigned long long bal = __ballot(m != 0);
        int below = __popcll(bal & ((1ULL << lane) - 1ULL));
        if (lane == 0) wt[w] = __popcll(bal);
        __syncthreads();
        int waveOfs = 0, total = 0;
#pragma unroll
        for (int j = 0; j < 4; ++j) { int c = wt[j]; if (j < w) waveOfs += c; total += c; }
        int rank = found + waveOfs + below;
        if (m && rank < 64) lds_node[rank] = i;
        found += total;
        __syncthreads();
    }

    // ---- phase 2: MLP ----
    int r = t >> 2;                  // staging row 0..63
    int q = t & 3;                   // staging quarter (16 floats)
    int n = lds_node[r];
    int nrow = (n >= 0) ? n : 0;     // invalid rows read row 0; outputs masked at write

    // issue the whole nf row segment for this thread now (chunks 0 and 1): one gather latency
    const float* srcN = nf + (size_t)nrow * 128 + q * 16;
    float4 fN[8];
#pragma unroll
    for (int i = 0; i < 4; ++i) {
        fN[i]     = *(const float4*)(srcN + i * 4);
        fN[4 + i] = *(const float4*)(srcN + 64 + i * 4);
    }

    f32x4 acc[2][4];
#pragma unroll
    for (int i = 0; i < 2; ++i)
#pragma unroll
        for (int j = 0; j < 4; ++j) acc[i][j] = (f32x4){0.f, 0.f, 0.f, 0.f};

    float4 fA[4];                    // gf prefetch window (chunks 2,3)

#pragma unroll
    for (int c = 0; c < 4; ++c) {
        {   // regs -> LDS (A)
            float4 s0 = (c == 0) ? fN[0] : (c == 1) ? fN[4] : fA[0];
            float4 s1 = (c == 0) ? fN[1] : (c == 1) ? fN[5] : fA[1];
            float4 s2 = (c == 0) ? fN[2] : (c == 1) ? fN[6] : fA[2];
            float4 s3 = (c == 0) ? fN[3] : (c == 1) ? fN[7] : fA[3];
            unsigned short tmp[16];
            tmp[0]  = f2bf(s0.x); tmp[1]  = f2bf(s0.y); tmp[2]  = f2bf(s0.z); tmp[3]  = f2bf(s0.w);
            tmp[4]  = f2bf(s1.x); tmp[5]  = f2bf(s1.y); tmp[6]  = f2bf(s1.z); tmp[7]  = f2bf(s1.w);
            tmp[8]  = f2bf(s2.x); tmp[9]  = f2bf(s2.y); tmp[10] = f2bf(s2.z); tmp[11] = f2bf(s2.w);
            tmp[12] = f2bf(s3.x); tmp[13] = f2bf(s3.y); tmp[14] = f2bf(s3.z); tmp[15] = f2bf(s3.w);
            *(bf16x8*)&ldsA[r][q * 16]     = *(bf16x8*)&tmp[0];
            *(bf16x8*)&ldsA[r][q * 16 + 8] = *(bf16x8*)&tmp[8];
            // regs -> LDS (B)
            *(bf16x8*)&ldsB[bcol][bh0]      = fB[0];
            *(bf16x8*)&ldsB[bcol][bh0 + 8]  = fB[1];
            *(bf16x8*)&ldsB[bcol][bh0 + 16] = fB[2];
            *(bf16x8*)&ldsB[bcol][bh0 + 24] = fB[3];
        }
        __syncthreads();
        if (c < 3) {                 // prefetch next W1T chunk
            const unsigned short* srcB = w1t + bcol * 256 + (c + 1) * 64 + bh0;
            fB[0] = *(const bf16x8*)(srcB);      fB[1] = *(const bf16x8*)(srcB + 8);
            fB[2] = *(const bf16x8*)(srcB + 16); fB[3] = *(const bf16x8*)(srcB + 24);
        }
        if (c == 1 || c == 2) {      // prefetch gf chunk (c+1 in {2,3})
            const float* srcG = gf + (size_t)blk * 128 + (c - 1) * 64 + q * 16;
            fA[0] = *(const float4*)(srcG);     fA[1] = *(const float4*)(srcG + 4);
            fA[2] = *(const float4*)(srcG + 8); fA[3] = *(const float4*)(srcG + 12);
        }
#pragma unroll
        for (int ks = 0; ks < 2; ++ks) {
            int ko = ks * 32 + (lane >> 4) * 8;
            bf16x8 af[2], bfr[4];
#pragma unroll
            for (int mt = 0; mt < 2; ++mt)
                af[mt] = *(const bf16x8*)&ldsA[wm * 32 + mt * 16 + (lane & 15)][ko];
#pragma unroll
            for (int nt = 0; nt < 4; ++nt)
                bfr[nt] = *(const bf16x8*)&ldsB[wn * 64 + nt * 16 + (lane & 15)][ko];
#pragma unroll
            for (int mt = 0; mt < 2; ++mt)
#pragma unroll
                for (int nt = 0; nt < 4; ++nt)
                    acc[mt][nt] = __builtin_amdgcn_mfma_f32_16x16x32_bf16(
                        af[mt], bfr[nt], acc[mt][nt], 0, 0, 0);
        }
        __syncthreads();
    }

    // layer1 epilogue: bias + relu -> ldsH (aliases ldsA/ldsB, which are dead now)
#pragma unroll
    for (int nt = 0; nt < 4; ++nt) {
        int col = wn * 64 + nt * 16 + (lane & 15);
        float bias = b1v[nt];
#pragma unroll
        for (int mt = 0; mt < 2; ++mt) {
            int row0 = wm * 32 + mt * 16 + (lane >> 4) * 4;
#pragma unroll
            for (int rr = 0; rr < 4; ++rr) {
                float v = acc[mt][nt][rr] + bias;
                v = v > 0.f ? v : 0.f;
                ldsH[row0 + rr][col] = f2bf(v);
            }
        }
    }
    __syncthreads();

    // layer2: wave w handles rows [w*16,+16); K=128 in 4 steps; cols 0..31 (pad of 24)
    f32x4 acc2[2];
    acc2[0] = (f32x4){0.f, 0.f, 0.f, 0.f};
    acc2[1] = (f32x4){0.f, 0.f, 0.f, 0.f};
#pragma unroll
    for (int ks = 0; ks < 4; ++ks) {
        int ko = ks * 32 + (lane >> 4) * 8;
        bf16x8 a2 = *(const bf16x8*)&ldsH[w * 16 + (lane & 15)][ko];
#pragma unroll
        for (int ct = 0; ct < 2; ++ct) {
            bf16x8 bw = *(const bf16x8*)&ldsW2[ct * 16 + (lane & 15)][ko];
            acc2[ct] = __builtin_amdgcn_mfma_f32_16x16x32_bf16(a2, bw, acc2[ct], 0, 0, 0);
        }
    }

    // write out: every (slot, m<24) element written exactly once per call
#pragma unroll
    for (int ct = 0; ct < 2; ++ct) {
        int m = ct * 16 + (lane & 15);
        if (m >= 24) continue;
#pragma unroll
        for (int rr = 0; rr < 4; ++rr) {
            int row = w * 16 + (lane >> 4) * 4 + rr;
            size_t oidx = (size_t)(blk * 64 + row) * 24 + m;
            float v = acc2[ct][rr] + b2v[ct];
            bool keep = (lds_node[row] >= 0) && (mmv[ct * 4 + rr] != 0);
            out[oidx] = keep ? v : NEGV;
        }
    }
}

// ---------------- launcher ----------------
extern "C" void kernel_launch(void* const* d_in, const int* in_sizes, int n_in,
                              void* d_out, int out_size, void* d_ws, size_t ws_size,
                              hipStream_t stream) {
    const float* nf = (const float*)d_in[0];
    const float* gf = (const float*)d_in[1];
    const float* W1 = (const float*)d_in[2];
    const float* b1 = (const float*)d_in[3];
    const float* W2 = (const float*)d_in[4];
    const float* b2 = (const float*)d_in[5];
    const int* cube_mask = (const int*)d_in[6];
    const int* batch     = (const int*)d_in[7];
    const int* move_mask = (const int*)d_in[8];
    float* out = (float*)d_out;

    int N = in_sizes[6];            // 500000
    int B = in_sizes[1] / 128;      // 512

    char* ws = (char*)d_ws;
    int* batch_start = (int*)(ws);                         // B+1 ints
    unsigned short* w1t = (unsigned short*)(ws + 4096);    // 128*256 bf16 (64 KB)
    unsigned short* w2t = (unsigned short*)(ws + 69632);   // 32*128 bf16 (8 KB)

    int NB = (N + 255) / 256;       // 1954
    prep_kernel<<<NB, 256, 0, stream>>>(W1, W2, batch, N, B, batch_start, w1t, w2t);
    fused_kernel<<<B, 256, 0, stream>>>(nf, gf, w1t, w2t, b1, b2,
                                        cube_mask, batch_start, move_mask, out);
    (void)n_in; (void)out_size; (void)ws_size;
}